// Round 3
// baseline (236.043 us; speedup 1.0000x reference)
//
#include <hip/hip_runtime.h>
#include <hip/hip_bf16.h>

#define RCOEF 1.0f
#define P1    0.5f

typedef float f32x4 __attribute__((ext_vector_type(4)));
typedef int   i32x4 __attribute__((ext_vector_type(4)));

__global__ __launch_bounds__(256) void loss_kernel(
    const float* __restrict__ final_out,
    const int*   __restrict__ point_victor,
    float*       __restrict__ out,
    int n, float denom)
{
    const long long tid    = (long long)blockIdx.x * blockDim.x + threadIdx.x;
    const long long stride = (long long)gridDim.x * blockDim.x;

    const f32x4* fo4 = (const f32x4*)final_out;
    const i32x4* pv4 = (const i32x4*)point_victor;
    const long long ngroups = n >> 3;   // groups of 8 points

    double acc = 0.0;

    for (long long g = tid; g < ngroups; g += stride) {
        // points 8g .. 8g+7: 4x float4 (2 points each) + 2x int4
        f32x4 a = __builtin_nontemporal_load(&fo4[4 * g]);
        f32x4 b = __builtin_nontemporal_load(&fo4[4 * g + 1]);
        f32x4 c = __builtin_nontemporal_load(&fo4[4 * g + 2]);
        f32x4 d = __builtin_nontemporal_load(&fo4[4 * g + 3]);
        i32x4 u = __builtin_nontemporal_load(&pv4[2 * g]);
        i32x4 v = __builtin_nontemporal_load(&pv4[2 * g + 1]);

        float pw0 = (u.x == 0) ? a.x : a.y;
        float pw1 = (u.y == 0) ? a.z : a.w;
        float pw2 = (u.z == 0) ? b.x : b.y;
        float pw3 = (u.w == 0) ? b.z : b.w;
        float pw4 = (v.x == 0) ? c.x : c.y;
        float pw5 = (v.y == 0) ? c.z : c.w;
        float pw6 = (v.z == 0) ? d.x : d.y;
        float pw7 = (v.w == 0) ? d.z : d.w;

        float d0 = a.x - P1, d1 = a.z - P1, d2 = b.x - P1, d3 = b.z - P1;
        float d4 = c.x - P1, d5 = c.z - P1, d6 = d.x - P1, d7 = d.z - P1;

        float e0 = logf(pw0) - RCOEF * d0 * d0;
        float e1 = logf(pw1) - RCOEF * d1 * d1;
        float e2 = logf(pw2) - RCOEF * d2 * d2;
        float e3 = logf(pw3) - RCOEF * d3 * d3;
        float e4 = logf(pw4) - RCOEF * d4 * d4;
        float e5 = logf(pw5) - RCOEF * d5 * d5;
        float e6 = logf(pw6) - RCOEF * d6 * d6;
        float e7 = logf(pw7) - RCOEF * d7 * d7;

        const float base = (float)(g << 3);   // exact: < 2^24
        float r0 = (base        ) / denom;
        float r1 = (base + 1.0f) / denom;
        float r2 = (base + 2.0f) / denom;
        float r3 = (base + 3.0f) / denom;
        float r4 = (base + 4.0f) / denom;
        float r5 = (base + 5.0f) / denom;
        float r6 = (base + 6.0f) / denom;
        float r7 = (base + 7.0f) / denom;

        acc += (double)(e0 * r0 + e1 * r1) + (double)(e2 * r2 + e3 * r3)
             + (double)(e4 * r4 + e5 * r5) + (double)(e6 * r6 + e7 * r7);
    }

    // scalar tail (n not multiple of 8)
    for (long long i = (ngroups << 3) + tid; i < n; i += stride) {
        float p0  = final_out[2 * i];
        float p1v = final_out[2 * i + 1];
        float pw  = (point_victor[i] == 0) ? p0 : p1v;
        float dd  = p0 - P1;
        float e   = logf(pw) - RCOEF * dd * dd;
        float r   = (float)i / denom;
        acc += (double)(e * r);
    }

    // wave-64 butterfly reduce (double)
    for (int off = 32; off > 0; off >>= 1)
        acc += __shfl_down(acc, off, 64);

    __shared__ double warp_sums[4];   // 256 threads / 64
    const int wave = threadIdx.x >> 6;
    if ((threadIdx.x & 63) == 0) warp_sums[wave] = acc;
    __syncthreads();

    if (threadIdx.x == 0) {
        double s = warp_sums[0] + warp_sums[1] + warp_sums[2] + warp_sums[3];
        atomicAdd(out, -(float)s);    // loss = -sum
    }
}

extern "C" void kernel_launch(void* const* d_in, const int* in_sizes, int n_in,
                              void* d_out, int out_size, void* d_ws, size_t ws_size,
                              hipStream_t stream) {
    const float* final_out    = (const float*)d_in[0];
    const int*   point_victor = (const int*)d_in[1];
    float*       out          = (float*)d_out;

    const int n = in_sizes[1];   // point_victor has n elements; final_out has 2n

    // denom exactly as the reference computes it in float32
    const float denom = (float)n * (float)(n + 1) * 0.5f;

    (void)hipMemsetAsync(d_out, 0, sizeof(float), stream);

    const int threads = 256;
    const int blocks  = 2048;   // 2048*256 threads; 8 pts/thread/iter -> 4 iters, no tail at n=2^24
    loss_kernel<<<blocks, threads, 0, stream>>>(final_out, point_victor, out, n, denom);
}